// Round 9
// baseline (171.683 us; speedup 1.0000x reference)
//
#include <hip/hip_runtime.h>

// Radon transform, MI355X. B=4, IMG=256, NA=512.
// R9: batch-pairing. A block stages TWO batch images' quad slabs (2x39.4 KB
// LDS) and computes both batches' samples per coordinate: the ~10-instr
// coordinate work (advance/floor/fract/addr/weights) is shared; marginal
// batch cost = 1 ds_read_b64 (same addr + imm offset) + 3 VALU. ~8 VALU/sample
// vs R8's ~14.5 (R8 was VALU-bound: 81% busy). Clamps eliminated via 2-wide
// zero margins + floor-consistent (int)floorf/fract indexing.

typedef _Float16 f16;
typedef _Float16 f16x2 __attribute__((ext_vector_type(2)));
typedef _Float16 f16x4 __attribute__((ext_vector_type(4)));
typedef __fp16   h16x2 __attribute__((ext_vector_type(2)));
typedef float    f32x2 __attribute__((ext_vector_type(2)));

#define NQ    19                 // quad rows per slab (Ri in [0,18])
#define NCQ   259                // quad cols X = 0..258 (cols X-2, X-1)
#define QPB   (NCQ * NQ)         // 4921 quads per batch-slab
                                 // LDS total 2*QPB*8 = 78,736 B -> 2 blocks/CU

// one h-step, both batches: quad (X,Ri) = {P[r][X-2],P[r][X-1],
// P[r+1][X-2],P[r+1][X-1]}, r = rbase+Ri. Two ds_read_b64 at one address
// (+imm offset QPB*8). floor/fract consistent; margins absorb FP drift.
#define SAMP2(POS, A0, A1) do {                                   \
    float pc_ = (POS).x, pr_ = (POS).y;                           \
    int   Xi_ = (int)floorf(pc_);                                 \
    int   Ri_ = (int)floorf(pr_);                                 \
    float wc_ = __builtin_amdgcn_fractf(pc_);                     \
    float wr_ = __builtin_amdgcn_fractf(pr_);                     \
    int   e_  = Xi_ * NQ + Ri_;                                   \
    f16x4 q0_ = lds4[e_];                                         \
    f16x4 q1_ = lds4[e_ + QPB];                                   \
    f16x2 wv_ = __builtin_bit_cast(f16x2, __builtin_amdgcn_cvt_pkrtz(wr_, wr_)); \
    h16x2 wp_ = __builtin_amdgcn_cvt_pkrtz(1.0f - wc_, wc_);      \
    f16x2 lo0_ = __builtin_shufflevector(q0_, q0_, 0, 1);         \
    f16x2 hi0_ = __builtin_shufflevector(q0_, q0_, 2, 3);         \
    f16x2 t0_  = lo0_ + wv_ * (hi0_ - lo0_);                      \
    (A0) = __builtin_amdgcn_fdot2(__builtin_bit_cast(h16x2, t0_), wp_, (A0), false); \
    f16x2 lo1_ = __builtin_shufflevector(q1_, q1_, 0, 1);         \
    f16x2 hi1_ = __builtin_shufflevector(q1_, q1_, 2, 3);         \
    f16x2 t1_  = lo1_ + wv_ * (hi1_ - lo1_);                      \
    (A1) = __builtin_amdgcn_fdot2(__builtin_bit_cast(h16x2, t1_), wp_, (A1), false); \
} while (0)

__global__ __launch_bounds__(256) void transpose_k(const float* __restrict__ img,
                                                   float* __restrict__ imT) {
    __shared__ float tl[32][33];
    const int bx = blockIdx.x;                    // 256 = b(4) x ty(8) x tx(8)
    const int x0 = (bx & 7) << 5, y0 = ((bx >> 3) & 7) << 5, b = bx >> 6;
    const int lane = threadIdx.x & 31, rw = threadIdx.x >> 5;
    const float* ib = img + (b << 16);
    float*       tb = imT + (b << 16);
#pragma unroll
    for (int p = 0; p < 4; ++p) {
        int row = rw + (p << 3);
        tl[row][lane] = ib[((y0 + row) << 8) + x0 + lane];
    }
    __syncthreads();
#pragma unroll
    for (int p = 0; p < 4; ++p) {
        int row = rw + (p << 3);
        tb[((x0 + row) << 8) + y0 + lane] = tl[lane][row];
    }
}

__global__ __launch_bounds__(512, 4) void radon_k(const float* __restrict__ img,
                                                  const float* __restrict__ imT,
                                                  float* __restrict__ ws2) {
    __shared__ f16x4 lds4[2 * QPB];
    const int tid = threadIdx.x;
    const int bx  = blockIdx.x;                 // 1024 = bp(2) x g(64) x q2(8)
    const int q2 = bx & 7, g = (bx >> 3) & 63, bp = bx >> 9;
    const bool colC = (g >= 16) && (g < 48);    // a in [128,384): column slabs
    const float* base = colC ? imT : img;
    const float* src0 = base + ((bp << 1) << 16);
    const float* src1 = base + (((bp << 1) | 1) << 16);

    const int   w   = tid & 255, sub = tid >> 8;  // angle uniform per wave
    const float xw  = (float)w - 127.5f;

    float accA[4] = {0.f, 0.f, 0.f, 0.f};       // batch bp*2
    float accB[4] = {0.f, 0.f, 0.f, 0.f};       // batch bp*2+1

    for (int s = 0; s < 2; ++s) {
        const int q = (q2 << 1) | s;            // slab 0..15 (16 rows each)
        const int rbase = (q << 4) - 2;         // 2-row zero margin below
        if (s) __syncthreads();                 // drain slab-0 compute

        // ---- stage both batches' quads; X fastest -> coalesced
        for (int u = tid; u < 2 * QPB; u += 512) {
            const int bt = (u >= QPB);
            const int uu = u - (bt ? QPB : 0);
            const int Ri = uu / NCQ;            // 0..18
            const int X  = uu - Ri * NCQ;       // 0..258
            const int r0 = rbase + Ri;
            const int c0 = X - 2, c1 = X - 1;
            const float* sp = bt ? src1 : src0;
            float v00 = 0.f, v01 = 0.f, v10 = 0.f, v11 = 0.f;
            if ((unsigned)r0 < 256u) {
                const float* rp = sp + (r0 << 8);
                if ((unsigned)c0 < 256u) v00 = rp[c0];
                if ((unsigned)c1 < 256u) v01 = rp[c1];
            }
            if ((unsigned)(r0 + 1) < 256u) {
                const float* rp = sp + ((r0 + 1) << 8);
                if ((unsigned)c0 < 256u) v10 = rp[c0];
                if ((unsigned)c1 < 256u) v11 = rp[c1];
            }
            f16x4 w4; w4.x = (f16)v00; w4.y = (f16)v01; w4.z = (f16)v10; w4.w = (f16)v11;
            lds4[bt * QPB + X * NQ + Ri] = w4;
        }
        __syncthreads();

        // band [B0,B1) on the slab axis
        const float B0 = (q == 0)  ? -1.0f  : (float)(q << 4);
        const float B1 = (q == 15) ? 256.0f : (float)((q << 4) + 16);

#pragma unroll
        for (int k = 0; k < 4; ++k) {
            const int a = (g << 3) | (k << 1) | sub;
            const float th  = (float)a * 6.1359231515425649e-3f;   // a*pi/512
            const float sth = __sinf(th), cth = __cosf(th);        // block-consistent
            const float Ax = fmaf(cth, xw, fmaf(sth, -127.5f, 127.5f));
            const float Ay = fmaf(-sth, xw, fmaf(cth, -127.5f, 127.5f));
            float cs, As, rs, Ar;                // col coord / slab coord roles
            if (colC) { cs = cth; As = Ay; rs = sth; Ar = Ax; }
            else      { cs = sth; As = Ax; rs = cth; Ar = Ay; }

            // slab ownership: r(h)=Ar+h*rs in [B0,B1); |rs|>=0.707; exact
            // ceil/floor partition (adjacent q share identical boundary floats)
            const float invr = 1.0f / rs;
            const float tA = (B0 - Ar) * invr, tB = (B1 - Ar) * invr;
            int h0, h1;
            if (rs > 0.f) { h0 = (int)ceilf(tA);      h1 = (int)ceilf(tB) - 1; }
            else          { h0 = (int)floorf(tB) + 1; h1 = (int)floorf(tA);   }

            // col validity v(h)=As+h*cs in (-1,256); cs signed, may be ~0
            if (cs != 0.f) {
                const float invc = 1.0f / cs;
                float ta = (-1.0f - As) * invc, tb = (256.0f - As) * invc;
                ta = fmaxf(fminf(ta, 400.f), -400.f);
                tb = fmaxf(fminf(tb, 400.f), -400.f);
                if (cs > 0.f) { h0 = max(h0, (int)ceilf(ta));      h1 = min(h1, (int)ceilf(tb) - 1); }
                else          { h0 = max(h0, (int)floorf(tb) + 1); h1 = min(h1, (int)floorf(ta));   }
            } else if (As <= -1.f || As >= 256.f) {
                h1 = h0 - 1;
            }
            h0 = max(h0, 0); h1 = min(h1, 255);

            if (h0 <= h1) {
                const float h0f = (float)h0;
                f32x2 pos0, st;
                pos0.x = fmaf(h0f, cs, As + 2.0f);           // col coord + 2
                pos0.y = fmaf(h0f, rs, Ar - (float)rbase);   // slab-local row
                st.x = cs; st.y = rs;
                f32x2 pA = pos0, pB = pos0 + st;
                const f32x2 st2 = st + st;
                float a00 = 0.f, a01 = 0.f, a10 = 0.f, a11 = 0.f;
                const int n = h1 - h0 + 1;                   // <= 24
                for (int i = 0; i + 2 <= n; i += 2) {        // dual h-chains
                    SAMP2(pA, a00, a01);
                    SAMP2(pB, a10, a11);
                    pA += st2; pB += st2;
                }
                if (n & 1) SAMP2(pA, a00, a01);
                accA[k] += a00 + a10;
                accB[k] += a01 + a11;
            }
        }
    }

#pragma unroll
    for (int k = 0; k < 4; ++k) {               // wave-coalesced 256B segments
        const int a  = (g << 3) | (k << 1) | sub;
        const int b0 = bp << 1;
        ws2[((((q2 << 2) + b0) << 9) | a) * 256 + w]       = accA[k];
        ws2[((((q2 << 2) + b0 + 1) << 9) | a) * 256 + w]   = accB[k];
    }
}

__global__ __launch_bounds__(256) void reduce_k(const float* __restrict__ ws2,
                                                float* __restrict__ out) {
    __shared__ float s[32][33];
    const int bx = blockIdx.x;                  // 512 = b(4) x at(16) x wt(8)
    const int wt = bx & 7, at = (bx >> 3) & 15, b = bx >> 7;
    const int a0 = at << 5, w0 = wt << 5;
    const int wl = threadIdx.x & 31, r8 = threadIdx.x >> 5;
#pragma unroll
    for (int p = 0; p < 4; ++p) {
        int ar = r8 + (p << 3);
        int a  = a0 + ar;
        float acc = 0.f;
#pragma unroll
        for (int qq = 0; qq < 8; ++qq)
            acc += ws2[(((((qq << 2) + b) << 9) | a) << 8) | (w0 + wl)];
        s[ar][wl] = acc;                        // s[a_local][w_local]
    }
    __syncthreads();
#pragma unroll
    for (int p = 0; p < 4; ++p) {
        int wr = r8 + (p << 3);
        out[(b << 17) | ((w0 + wr) << 9) | (a0 + wl)] = s[wl][wr];  // coalesced in a
    }
}

extern "C" void kernel_launch(void* const* d_in, const int* in_sizes, int n_in,
                              void* d_out, int out_size, void* d_ws, size_t ws_size,
                              hipStream_t stream) {
    const float* img = (const float*)d_in[0];
    float* out = (float*)d_out;
    float* imT = (float*)d_ws;                  // 1 MB transposed copy
    float* ws2 = (float*)d_ws + (1 << 18);      // 16.8 MB: [q2][b][a][w]
    transpose_k<<<dim3(256),  dim3(256), 0, stream>>>(img, imT);
    radon_k   <<<dim3(1024), dim3(512), 0, stream>>>(img, imT, ws2);
    reduce_k  <<<dim3(512),  dim3(256), 0, stream>>>(ws2, out);
}

// Round 10
// 135.058 us; speedup vs baseline: 1.2712x; 1.2712x over previous
//
#include <hip/hip_runtime.h>

// Radon transform, MI355X. B=4, IMG=256, NA=512.
// R10: batch-pairing (R9's VALU win) at 4 blocks/CU (R8's occupancy win).
// Vertical-pair LDS words (f16x2 = P[r][c],P[r+1][c]; 2x dup, not quad's 4x),
// column-major stride 19 -> sample reads words e,e+19 = ONE ds_read2_b32 per
// batch. 2 batches x 19,760 B = 39.5 KB -> 4 blocks/CU. Shared coord math
// ~13 VALU + 3 VALU/batch. transpose_k deleted: col-mode stages from img with
// Ri-fast ordering (~20 consecutive floats/row per lane group).

typedef _Float16 f16;
typedef _Float16 f16x2 __attribute__((ext_vector_type(2)));
typedef __fp16   h16x2 __attribute__((ext_vector_type(2)));
typedef float    f32x2 __attribute__((ext_vector_type(2)));

#define NR    19                 // padded pair-row stride (Ri 0..17 used, 18=pad)
#define NRW   18                 // written pair-rows per slab
#define NCX   260                // cols X' = 0..259 (image col X'-2)
#define WPB   (NCX * NR)         // 4940 words per batch-slab (19,760 B)
                                 // LDS total 2*WPB*4 = 39,520 B -> 4 blocks/CU

// one h-step, both batches. Word (X',Ri) = (P[rbase+Ri][X'-2], P[rbase+Ri+1][X'-2]).
// Words e,e+NR (cols c,c+1) -> ds_read2_b32. Packed horizontal lerp over the
// (r,r+1) pair; vertical lerp via fdot2(1-wr,wr). pc>=0.99 always (v>-1-eps),
// so trunc==floor; med3 on pr absorbs q-edge FP drift into zero-row words.
#define SAMP2(POS, A0, A1) do {                                   \
    float pc_ = (POS).x;                                          \
    float pr_ = __builtin_amdgcn_fmed3f((POS).y, 0.0f, 17.999f);  \
    int   Xi_ = (int)pc_;                                         \
    int   Ri_ = (int)pr_;                                         \
    float wc_ = __builtin_amdgcn_fractf(pc_);                     \
    float wr_ = __builtin_amdgcn_fractf(pr_);                     \
    int   e_  = Xi_ * NR + Ri_;                                   \
    f16x2 lo0_ = ldsP[e_];                                        \
    f16x2 hi0_ = ldsP[e_ + NR];                                   \
    f16x2 lo1_ = ldsP[e_ + WPB];                                  \
    f16x2 hi1_ = ldsP[e_ + WPB + NR];                             \
    f16x2 wcv_ = __builtin_bit_cast(f16x2, __builtin_amdgcn_cvt_pkrtz(wc_, wc_)); \
    h16x2 wpr_ = __builtin_amdgcn_cvt_pkrtz(1.0f - wr_, wr_);     \
    f16x2 t0_  = lo0_ + wcv_ * (hi0_ - lo0_);                     \
    f16x2 t1_  = lo1_ + wcv_ * (hi1_ - lo1_);                     \
    (A0) = __builtin_amdgcn_fdot2(__builtin_bit_cast(h16x2, t0_), wpr_, (A0), false); \
    (A1) = __builtin_amdgcn_fdot2(__builtin_bit_cast(h16x2, t1_), wpr_, (A1), false); \
} while (0)

__global__ __launch_bounds__(512, 8) void radon_k(const float* __restrict__ img,
                                                  float* __restrict__ ws2) {
    __shared__ f16x2 ldsP[2 * WPB];
    const int tid = threadIdx.x;
    const int bx  = blockIdx.x;                 // 1024 = bp(2) x g(64) x q2(8)
    const int q2 = bx & 7, g = (bx >> 3) & 63, bp = bx >> 9;
    const bool colC = (g >= 16) && (g < 48);    // a in [128,384): column slabs
    const float* src0 = img + ((bp << 1) << 16);
    const float* src1 = img + (((bp << 1) | 1) << 16);

    const int   w   = tid & 255, sub = tid >> 8;  // angle uniform per wave
    const float xw  = (float)w - 127.5f;

    float accA[4] = {0.f, 0.f, 0.f, 0.f};       // batch bp*2
    float accB[4] = {0.f, 0.f, 0.f, 0.f};       // batch bp*2+1

    for (int s = 0; s < 2; ++s) {
        const int q = (q2 << 1) | s;            // slab 0..15 (16 rows each)
        const int rbase = (q << 4) - 1;         // pair rows rbase..rbase+18
        if (s) __syncthreads();                 // drain slab-0 compute

        // ---- stage both batches directly from img
        for (int bt = 0; bt < 2; ++bt) {
            const float* sp = bt ? src1 : src0;
            f16x2* dst = ldsP + bt * WPB;
            if (!colC) {
                // row-mode: X' fastest -> coalesced; LDS write stride 19 (free)
                for (int u = tid; u < NCX * NRW; u += 512) {
                    int Ri = u / NCX;           // 0..17
                    int Xp = u - Ri * NCX;      // 0..259
                    int r0 = rbase + Ri;
                    int c  = Xp - 2;
                    float va = 0.f, vb = 0.f;
                    if ((unsigned)c < 256u) {
                        if ((unsigned)r0 < 256u)       va = sp[(r0 << 8) + c];
                        if ((unsigned)(r0 + 1) < 256u) vb = sp[((r0 + 1) << 8) + c];
                    }
                    dst[Xp * NR + Ri] = __builtin_bit_cast(f16x2,
                        __builtin_amdgcn_cvt_pkrtz(va, vb));
                }
            } else {
                // col-mode: view P'[x][y]=img[y][x]; Ri fastest -> lanes read
                // ~20 consecutive floats per img row (no transpose kernel)
                for (int u = tid; u < NCX * NRW; u += 512) {
                    int Xp = u / NRW;           // 0..259 (image row Xp-2)
                    int Ri = u - Xp * NRW;      // 0..17  (image col rbase+Ri)
                    int r  = Xp - 2;
                    int c0 = rbase + Ri;
                    float va = 0.f, vb = 0.f;
                    if ((unsigned)r < 256u) {
                        const float* rp = sp + (r << 8);
                        if ((unsigned)c0 < 256u)       va = rp[c0];
                        if ((unsigned)(c0 + 1) < 256u) vb = rp[c0 + 1];
                    }
                    dst[Xp * NR + Ri] = __builtin_bit_cast(f16x2,
                        __builtin_amdgcn_cvt_pkrtz(va, vb));
                }
            }
        }
        __syncthreads();

        // band [B0,B1) on the slab axis
        const float B0 = (q == 0)  ? -1.0f  : (float)(q << 4);
        const float B1 = (q == 15) ? 256.0f : (float)((q << 4) + 16);

#pragma unroll
        for (int k = 0; k < 4; ++k) {
            const int a = (g << 3) | (k << 1) | sub;
            const float th  = (float)a * 6.1359231515425649e-3f;   // a*pi/512
            const float sth = __sinf(th), cth = __cosf(th);        // block-consistent
            const float Ax = fmaf(cth, xw, fmaf(sth, -127.5f, 127.5f));
            const float Ay = fmaf(-sth, xw, fmaf(cth, -127.5f, 127.5f));
            float cs, As, rs, Ar;                // col coord / slab coord roles
            if (colC) { cs = cth; As = Ay; rs = sth; Ar = Ax; }
            else      { cs = sth; As = Ax; rs = cth; Ar = Ay; }

            // slab ownership: r(h)=Ar+h*rs in [B0,B1); |rs|>=0.707; exact
            // ceil/floor partition (adjacent q share identical boundary floats)
            const float invr = 1.0f / rs;
            const float tA = (B0 - Ar) * invr, tB = (B1 - Ar) * invr;
            int h0, h1;
            if (rs > 0.f) { h0 = (int)ceilf(tA);      h1 = (int)ceilf(tB) - 1; }
            else          { h0 = (int)floorf(tB) + 1; h1 = (int)floorf(tA);   }

            // col validity v(h)=As+h*cs in (-1,256); cs signed, may be ~0
            if (cs != 0.f) {
                const float invc = 1.0f / cs;
                float ta = (-1.0f - As) * invc, tb = (256.0f - As) * invc;
                ta = fmaxf(fminf(ta, 400.f), -400.f);
                tb = fmaxf(fminf(tb, 400.f), -400.f);
                if (cs > 0.f) { h0 = max(h0, (int)ceilf(ta));      h1 = min(h1, (int)ceilf(tb) - 1); }
                else          { h0 = max(h0, (int)floorf(tb) + 1); h1 = min(h1, (int)floorf(ta));   }
            } else if (As <= -1.f || As >= 256.f) {
                h1 = h0 - 1;
            }
            h0 = max(h0, 0); h1 = min(h1, 255);

            if (h0 <= h1) {
                const float h0f = (float)h0;
                f32x2 pos0, st;
                pos0.x = fmaf(h0f, cs, As + 2.0f);           // col coord + 2
                pos0.y = fmaf(h0f, rs, Ar - (float)rbase);   // slab-local pair row
                st.x = cs; st.y = rs;
                f32x2 pA = pos0, pB = pos0 + st;
                const f32x2 st2 = st + st;
                float a00 = 0.f, a01 = 0.f, a10 = 0.f, a11 = 0.f;
                const int n = h1 - h0 + 1;                   // <= 24
                for (int i = 0; i + 2 <= n; i += 2) {        // dual h-chains
                    SAMP2(pA, a00, a01);
                    SAMP2(pB, a10, a11);
                    pA += st2; pB += st2;
                }
                if (n & 1) SAMP2(pA, a00, a01);
                accA[k] += a00 + a10;
                accB[k] += a01 + a11;
            }
        }
    }

#pragma unroll
    for (int k = 0; k < 4; ++k) {               // wave-coalesced 256B segments
        const int a  = (g << 3) | (k << 1) | sub;
        const int b0 = bp << 1;
        ws2[((((q2 << 2) + b0) << 9) | a) * 256 + w]     = accA[k];
        ws2[((((q2 << 2) + b0 + 1) << 9) | a) * 256 + w] = accB[k];
    }
}

__global__ __launch_bounds__(256) void reduce_k(const float* __restrict__ ws2,
                                                float* __restrict__ out) {
    __shared__ float s[32][33];
    const int bx = blockIdx.x;                  // 512 = b(4) x at(16) x wt(8)
    const int wt = bx & 7, at = (bx >> 3) & 15, b = bx >> 7;
    const int a0 = at << 5, w0 = wt << 5;
    const int wl = threadIdx.x & 31, r8 = threadIdx.x >> 5;
#pragma unroll
    for (int p = 0; p < 4; ++p) {
        int ar = r8 + (p << 3);
        int a  = a0 + ar;
        float acc = 0.f;
#pragma unroll
        for (int qq = 0; qq < 8; ++qq)
            acc += ws2[(((((qq << 2) + b) << 9) | a) << 8) | (w0 + wl)];
        s[ar][wl] = acc;                        // s[a_local][w_local]
    }
    __syncthreads();
#pragma unroll
    for (int p = 0; p < 4; ++p) {
        int wr = r8 + (p << 3);
        out[(b << 17) | ((w0 + wr) << 9) | (a0 + wl)] = s[wl][wr];  // coalesced in a
    }
}

extern "C" void kernel_launch(void* const* d_in, const int* in_sizes, int n_in,
                              void* d_out, int out_size, void* d_ws, size_t ws_size,
                              hipStream_t stream) {
    const float* img = (const float*)d_in[0];
    float* out = (float*)d_out;
    float* ws2 = (float*)d_ws;                  // 16.8 MB: [q2][b][a][w]
    radon_k <<<dim3(1024), dim3(512), 0, stream>>>(img, ws2);
    reduce_k<<<dim3(512),  dim3(256), 0, stream>>>(ws2, out);
}

// Round 11
// 130.374 us; speedup vs baseline: 1.3168x; 1.0359x over previous
//
#include <hip/hip_runtime.h>

// Radon transform, MI355X. B=4, IMG=256, NA=512.
// R11: batch-INTERLEAVED LDS words. f16x4 = {b0[r][c], b0[r+1][c],
// b1[r][c], b1[r+1][c]}, column-major stride 19 -> a full dual-batch bilinear
// sample (8 taps) = words e,e+19 = ONE ds_read2_b64 (R10: 2x ds_read2_b32 =
// 4 accesses + extra addr add; DS pipe was ~54us vs VALU ~52us). LDS bytes
// unchanged (39.5 KB, batches share words) -> 4 blocks/CU kept. Packed f16x4
// horizontal lerp serves both batches; sincos hoisted out of the slab loop;
// triple h-chains (1 DS instr/step now).

typedef _Float16 f16;
typedef _Float16 f16x2 __attribute__((ext_vector_type(2)));
typedef _Float16 f16x4 __attribute__((ext_vector_type(4)));
typedef __fp16   h16x2 __attribute__((ext_vector_type(2)));
typedef float    f32x2 __attribute__((ext_vector_type(2)));

#define NR    19                 // padded slab-axis stride (Ri 0..17 used)
#define NRW   18                 // written slab-pair rows
#define NCX   260                // cols X' = 0..259 (col-axis value X'-2)
#define NWRD  (NCX * NR)         // 4940 f16x4 words = 39,520 B -> 4 blocks/CU

// one h-step, BOTH batches: word (X',Ri) spans slab-axis (r,r+1) x 2 batches
// at col c=X'-2; words e,e+NR = cols c,c+1 -> single ds_read2_b64.
// Horizontal (col) lerp packed over all 4 lanes; vertical (slab) lerp via
// fdot2 per batch. pc>=0.99 so trunc==floor; med3 on pr absorbs band-edge
// drift into zero-margin words.
#define SAMP2(POS, A0, A1) do {                                   \
    float pc_ = (POS).x;                                          \
    float pr_ = __builtin_amdgcn_fmed3f((POS).y, 0.0f, 17.999f);  \
    int   Xi_ = (int)pc_;                                         \
    int   Ri_ = (int)pr_;                                         \
    float wc_ = __builtin_amdgcn_fractf(pc_);                     \
    float wr_ = __builtin_amdgcn_fractf(pr_);                     \
    int   e_  = Xi_ * NR + Ri_;                                   \
    f16x4 lo_ = ldsQ[e_];                                         \
    f16x4 hi_ = ldsQ[e_ + NR];                                    \
    f16x2 wc2_ = __builtin_bit_cast(f16x2, __builtin_amdgcn_cvt_pkrtz(wc_, wc_)); \
    f16x4 wc4_ = __builtin_shufflevector(wc2_, wc2_, 0, 1, 0, 1); \
    f16x4 t_   = lo_ + wc4_ * (hi_ - lo_);                        \
    h16x2 wr2_ = __builtin_amdgcn_cvt_pkrtz(1.0f - wr_, wr_);     \
    h16x2 t0_  = __builtin_bit_cast(h16x2, __builtin_shufflevector(t_, t_, 0, 1)); \
    h16x2 t1_  = __builtin_bit_cast(h16x2, __builtin_shufflevector(t_, t_, 2, 3)); \
    (A0) = __builtin_amdgcn_fdot2(t0_, wr2_, (A0), false);        \
    (A1) = __builtin_amdgcn_fdot2(t1_, wr2_, (A1), false);        \
} while (0)

__global__ __launch_bounds__(512, 8) void radon_k(const float* __restrict__ img,
                                                  float* __restrict__ ws2) {
    __shared__ f16x4 ldsQ[NWRD];
    const int tid = threadIdx.x;
    const int bx  = blockIdx.x;                 // 1024 = bp(2) x g(64) x q2(8)
    const int q2 = bx & 7, g = (bx >> 3) & 63, bp = bx >> 9;
    const bool colC = (g >= 16) && (g < 48);    // a in [128,384): column slabs
    const float* src0 = img + ((bp << 1) << 16);
    const float* src1 = img + (((bp << 1) | 1) << 16);

    const int   w   = tid & 255, sub = tid >> 8;  // angle uniform per wave
    const float xw  = (float)w - 127.5f;

    // hoisted per-angle trig (same for both slabs)
    float sv[4], cv[4];
#pragma unroll
    for (int k = 0; k < 4; ++k) {
        const int a = (g << 3) | (k << 1) | sub;
        const float th = (float)a * 6.1359231515425649e-3f;   // a*pi/512
        sv[k] = __sinf(th); cv[k] = __cosf(th);               // block-consistent
    }

    float accA[4] = {0.f, 0.f, 0.f, 0.f};       // batch bp*2
    float accB[4] = {0.f, 0.f, 0.f, 0.f};       // batch bp*2+1

    for (int s = 0; s < 2; ++s) {
        const int q = (q2 << 1) | s;            // slab 0..15 (16 rows each)
        const int rbase = (q << 4) - 1;         // slab-axis pairs rbase..rbase+18
        if (s) __syncthreads();                 // drain slab-0 compute

        // ---- stage interleaved words for both batches
        if (!colC) {
            // row-mode: slab axis = image row. X' fastest -> 4 coalesced streams
            for (int u = tid; u < NCX * NRW; u += 512) {
                int Ri = u / NCX;               // 0..17
                int Xp = u - Ri * NCX;          // 0..259
                int r0 = rbase + Ri;
                int c  = Xp - 2;
                float v00 = 0.f, v01 = 0.f, v10 = 0.f, v11 = 0.f;
                if ((unsigned)c < 256u) {
                    if ((unsigned)r0 < 256u) {
                        v00 = src0[(r0 << 8) + c];
                        v10 = src1[(r0 << 8) + c];
                    }
                    if ((unsigned)(r0 + 1) < 256u) {
                        v01 = src0[((r0 + 1) << 8) + c];
                        v11 = src1[((r0 + 1) << 8) + c];
                    }
                }
                uint2 pk;
                pk.x = __builtin_bit_cast(unsigned, __builtin_amdgcn_cvt_pkrtz(v00, v01));
                pk.y = __builtin_bit_cast(unsigned, __builtin_amdgcn_cvt_pkrtz(v10, v11));
                ((uint2*)ldsQ)[Xp * NR + Ri] = pk;
            }
        } else {
            // col-mode: slab axis = image column -> word taps are horizontally
            // adjacent in img; Ri fastest so lanes read ~19 consecutive floats
            for (int u = tid; u < NCX * NRW; u += 512) {
                int Xp = u / NRW;               // 0..259 (image row r = Xp-2)
                int Ri = u - Xp * NRW;          // 0..17  (image col c0 = rbase+Ri)
                int r  = Xp - 2;
                int c0 = rbase + Ri;
                float v00 = 0.f, v01 = 0.f, v10 = 0.f, v11 = 0.f;
                if ((unsigned)r < 256u) {
                    const float* rp0 = src0 + (r << 8);
                    const float* rp1 = src1 + (r << 8);
                    if ((unsigned)c0 < 256u)       { v00 = rp0[c0];     v10 = rp1[c0]; }
                    if ((unsigned)(c0 + 1) < 256u) { v01 = rp0[c0 + 1]; v11 = rp1[c0 + 1]; }
                }
                uint2 pk;
                pk.x = __builtin_bit_cast(unsigned, __builtin_amdgcn_cvt_pkrtz(v00, v01));
                pk.y = __builtin_bit_cast(unsigned, __builtin_amdgcn_cvt_pkrtz(v10, v11));
                ((uint2*)ldsQ)[Xp * NR + Ri] = pk;
            }
        }
        __syncthreads();

        // band [B0,B1) on the slab axis
        const float B0 = (q == 0)  ? -1.0f  : (float)(q << 4);
        const float B1 = (q == 15) ? 256.0f : (float)((q << 4) + 16);

#pragma unroll
        for (int k = 0; k < 4; ++k) {
            const float sth = sv[k], cth = cv[k];
            const float Ax = fmaf(cth, xw, fmaf(sth, -127.5f, 127.5f));
            const float Ay = fmaf(-sth, xw, fmaf(cth, -127.5f, 127.5f));
            float cs, As, rs, Ar;                // col coord / slab coord roles
            if (colC) { cs = cth; As = Ay; rs = sth; Ar = Ax; }
            else      { cs = sth; As = Ax; rs = cth; Ar = Ay; }

            // slab ownership: r(h)=Ar+h*rs in [B0,B1); |rs|>=0.707; exact
            // ceil/floor partition (adjacent q share identical boundary floats)
            const float invr = 1.0f / rs;
            const float tA = (B0 - Ar) * invr, tB = (B1 - Ar) * invr;
            int h0, h1;
            if (rs > 0.f) { h0 = (int)ceilf(tA);      h1 = (int)ceilf(tB) - 1; }
            else          { h0 = (int)floorf(tB) + 1; h1 = (int)floorf(tA);   }

            // col validity v(h)=As+h*cs in (-1,256); cs signed, may be ~0
            if (cs != 0.f) {
                const float invc = 1.0f / cs;
                float ta = (-1.0f - As) * invc, tb = (256.0f - As) * invc;
                ta = fmaxf(fminf(ta, 400.f), -400.f);
                tb = fmaxf(fminf(tb, 400.f), -400.f);
                if (cs > 0.f) { h0 = max(h0, (int)ceilf(ta));      h1 = min(h1, (int)ceilf(tb) - 1); }
                else          { h0 = max(h0, (int)floorf(tb) + 1); h1 = min(h1, (int)floorf(ta));   }
            } else if (As <= -1.f || As >= 256.f) {
                h1 = h0 - 1;
            }
            h0 = max(h0, 0); h1 = min(h1, 255);

            if (h0 <= h1) {
                const float h0f = (float)h0;
                f32x2 pos0, st;
                pos0.x = fmaf(h0f, cs, As + 2.0f);           // col coord + 2
                pos0.y = fmaf(h0f, rs, Ar - (float)rbase);   // slab-local coord
                st.x = cs; st.y = rs;
                f32x2 pA = pos0, pB = pos0 + st, pC = pB + st;
                const f32x2 st3 = st + st + st;
                float a00 = 0.f, a01 = 0.f, a10 = 0.f, a11 = 0.f, a20 = 0.f, a21 = 0.f;
                const int n = h1 - h0 + 1;                   // <= 24
                int i = 0;
                for (; i + 3 <= n; i += 3) {                 // triple h-chains
                    SAMP2(pA, a00, a01);
                    SAMP2(pB, a10, a11);
                    SAMP2(pC, a20, a21);
                    pA += st3; pB += st3; pC += st3;
                }
                if (i + 1 <= n) SAMP2(pA, a00, a01);
                if (i + 2 <= n) SAMP2(pB, a10, a11);
                accA[k] += a00 + a10 + a20;
                accB[k] += a01 + a11 + a21;
            }
        }
    }

#pragma unroll
    for (int k = 0; k < 4; ++k) {               // wave-coalesced 256B segments
        const int a  = (g << 3) | (k << 1) | sub;
        const int b0 = bp << 1;
        ws2[((((q2 << 2) + b0) << 9) | a) * 256 + w]     = accA[k];
        ws2[((((q2 << 2) + b0 + 1) << 9) | a) * 256 + w] = accB[k];
    }
}

__global__ __launch_bounds__(256) void reduce_k(const float* __restrict__ ws2,
                                                float* __restrict__ out) {
    __shared__ float s[32][33];
    const int bx = blockIdx.x;                  // 512 = b(4) x at(16) x wt(8)
    const int wt = bx & 7, at = (bx >> 3) & 15, b = bx >> 7;
    const int a0 = at << 5, w0 = wt << 5;
    const int wl = threadIdx.x & 31, r8 = threadIdx.x >> 5;
#pragma unroll
    for (int p = 0; p < 4; ++p) {
        int ar = r8 + (p << 3);
        int a  = a0 + ar;
        float acc = 0.f;
#pragma unroll
        for (int qq = 0; qq < 8; ++qq)
            acc += ws2[(((((qq << 2) + b) << 9) | a) << 8) | (w0 + wl)];
        s[ar][wl] = acc;                        // s[a_local][w_local]
    }
    __syncthreads();
#pragma unroll
    for (int p = 0; p < 4; ++p) {
        int wr = r8 + (p << 3);
        out[(b << 17) | ((w0 + wr) << 9) | (a0 + wl)] = s[wl][wr];  // coalesced in a
    }
}

extern "C" void kernel_launch(void* const* d_in, const int* in_sizes, int n_in,
                              void* d_out, int out_size, void* d_ws, size_t ws_size,
                              hipStream_t stream) {
    const float* img = (const float*)d_in[0];
    float* out = (float*)d_out;
    float* ws2 = (float*)d_ws;                  // 16.8 MB: [q2][b][a][w]
    radon_k <<<dim3(1024), dim3(512), 0, stream>>>(img, ws2);
    reduce_k<<<dim3(512),  dim3(256), 0, stream>>>(ws2, out);
}